// Round 5
// baseline (2089.116 us; speedup 1.0000x reference)
//
#include <hip/hip_runtime.h>
#include <hip/hip_bf16.h>
#include <stdint.h>

// GPT self-attention, B=4 S=2048 E=2048 D=2048. FP32 in/out, bf16 MFMA internally.
// Round-5: (1) proj fuses Q/K/V into one block (A-tile reuse x3, BK=32, 32 KB LDS,
// 48 MFMA/barrier); (2) pv 2-wide in N (halved P staging, 64 MFMA/barrier);
// (3) masked score region never written/read (scores skips fill; softmax masks by
// index, zero-pads only to the 128-tile boundary pv actually reads).
// ws (184 MiB): Wqb|Wkb|Wvb bf16 | xb bf16[8192x2048] | Kall bf16 | Vtall bf16[b][d][s]
//               | Sc fp32[b][s][s]. Q bf16 lives in d_out (pv overwrites after use).

typedef unsigned short u16;
typedef unsigned int u32;
typedef __bf16 bf16x8 __attribute__((ext_vector_type(8)));
typedef float floatx4 __attribute__((ext_vector_type(4)));

#define DEVI __device__ __forceinline__

constexpr int Bn = 4, Sn = 2048, En = 2048, Dn = 2048;
constexpr int BM = 128;

DEVI u16 f2b(float f) {  // round-to-nearest-even f32 -> bf16
  union { float f; u32 u; } v; v.f = f;
  u32 r = v.u + 0x7FFFu + ((v.u >> 16) & 1u);
  return (u16)(r >> 16);
}

DEVI void cp16(const u16* g, u16* l) {  // async global->LDS, 16 B per lane
  __builtin_amdgcn_global_load_lds(
      (const __attribute__((address_space(1))) void*)g,
      (__attribute__((address_space(3))) void*)l, 16, 0, 0);
}

// ---- fp32 -> bf16 elementwise, n multiple of 2048; 8 elems/thread.
__global__ __launch_bounds__(256)
void cvt_kernel(const float* __restrict__ src, u16* __restrict__ dst, int n) {
  int i = (blockIdx.x * 256 + threadIdx.x) * 8;
  if (i >= n) return;
  float4 a = *(const float4*)&src[i];
  float4 b = *(const float4*)&src[i + 4];
  *(ushort4*)&dst[i]     = make_ushort4(f2b(a.x), f2b(a.y), f2b(a.z), f2b(a.w));
  *(ushort4*)&dst[i + 4] = make_ushort4(f2b(b.x), f2b(b.y), f2b(b.z), f2b(b.w));
}

// Multi-B GEMM core: acc[z] += Atile * Btile[z]^T for z in [0,ZB).
// Tiles 128 x BKT bf16 in LDS, XOR source-swizzle so DMA staging (wave-uniform
// base + lane*16) coexists with conflict-free ds_read_b128 fragment reads:
//   BKT=64: group g of row r stored at g^(r&7); BKT=32: g^((r>>1)&3).
// Fragment maps (m89/m91/m92): A[m=lane&15][k=quad*8+j], Bt[n=lane&15][k],
// C/D col=lane&15, row=quad*4+reg.  Ap/Bp are tile base pointers (m0/n0 applied).
template <int ZB, int BKT>
DEVI void gemm_multi(const u16* __restrict__ Ap, const u16* __restrict__ Bp0,
                     const u16* __restrict__ Bp1, const u16* __restrict__ Bp2,
                     size_t lda, size_t ldb, int kEnd,
                     u16* As, u16* Bs, floatx4 (*acc)[4][4]) {
  constexpr int GR = BKT / 8;        // 16B groups per row
  constexpr int CH = 128 * BKT / 8;  // chunks per tile
  constexpr int TE = 128 * BKT;      // elems per tile
  constexpr int CPT = CH / 256;      // chunks per thread per tile
  const int tid = threadIdx.x;
  const int lane = tid & 63;
  const int wave = tid >> 6;
  const int quad = lane >> 4;
  const int l16 = lane & 15;
  const int wm = (wave >> 1) * 64;
  const int wn = (wave & 1) * 64;

  int srow[CPT], sgl[CPT], sdst[CPT];
#pragma unroll
  for (int u = 0; u < CPT; ++u) {
    int c0 = wave * (CH / 4) + u * 64;  // wave-uniform chunk base
    int c = c0 + lane;
    int row = c / GR;
    int key = (BKT == 64) ? (row & 7) : ((row >> 1) & 3);
    srow[u] = row;
    sgl[u] = (c % GR) ^ key;
    sdst[u] = c0 * 8;
  }

  for (int k0 = 0; k0 < kEnd; k0 += BKT) {
#pragma unroll
    for (int u = 0; u < CPT; ++u) {
      cp16(Ap + (size_t)srow[u] * lda + k0 + sgl[u] * 8, As + sdst[u]);
      cp16(Bp0 + (size_t)srow[u] * ldb + k0 + sgl[u] * 8, Bs + sdst[u]);
      if constexpr (ZB > 1)
        cp16(Bp1 + (size_t)srow[u] * ldb + k0 + sgl[u] * 8, Bs + TE + sdst[u]);
      if constexpr (ZB > 2)
        cp16(Bp2 + (size_t)srow[u] * ldb + k0 + sgl[u] * 8, Bs + 2 * TE + sdst[u]);
    }
    __syncthreads();
#pragma unroll
    for (int s = 0; s < BKT / 32; ++s) {
      bf16x8 af[4];
#pragma unroll
      for (int i = 0; i < 4; ++i) {
        int R = wm + i * 16 + l16;
        int key = (BKT == 64) ? (R & 7) : ((R >> 1) & 3);
        int p = (s * 4 + quad) ^ key;
        af[i] = *(const bf16x8*)&As[R * BKT + p * 8];
      }
#pragma unroll
      for (int z = 0; z < ZB; ++z) {
        bf16x8 bfr[4];
#pragma unroll
        for (int j = 0; j < 4; ++j) {
          int R = wn + j * 16 + l16;
          int key = (BKT == 64) ? (R & 7) : ((R >> 1) & 3);
          int p = (s * 4 + quad) ^ key;
          bfr[j] = *(const bf16x8*)&Bs[z * TE + R * BKT + p * 8];
        }
#pragma unroll
        for (int i = 0; i < 4; ++i)
#pragma unroll
          for (int j = 0; j < 4; ++j)
            acc[z][i][j] =
                __builtin_amdgcn_mfma_f32_16x16x32_bf16(af[i], bfr[j], acc[z][i][j], 0, 0, 0);
      }
    }
    __syncthreads();
  }
}

// ---- fused QKV projection: one block -> Q,K,V tiles for (m0,n0). x staged once.
__global__ __launch_bounds__(256, 3)
void proj3_kernel(const u16* __restrict__ x, const u16* __restrict__ Wq,
                  const u16* __restrict__ Wk, const u16* __restrict__ Wv,
                  u16* __restrict__ Q, u16* __restrict__ K, u16* __restrict__ Vt) {
  __shared__ __align__(16) u16 As[128 * 32], Bs[3 * 128 * 32];  // 8 + 24 KB
  const int m0 = blockIdx.y * BM, n0 = blockIdx.x * BM;
  floatx4 acc[3][4][4] = {};
  gemm_multi<3, 32>(x + (size_t)m0 * En, Wq + (size_t)n0 * En, Wk + (size_t)n0 * En,
                    Wv + (size_t)n0 * En, En, En, En, As, Bs, acc);

  const int lane = threadIdx.x & 63, wave = threadIdx.x >> 6;
  const int wm = (wave >> 1) * 64, wn = (wave & 1) * 64;
  const int quad = lane >> 4, l16 = lane & 15;

#pragma unroll
  for (int i = 0; i < 4; ++i) {
    int t0 = m0 + wm + i * 16 + quad * 4;  // token index (0..8191)
    int b = t0 >> 11, s0 = t0 & (Sn - 1);
#pragma unroll
    for (int j = 0; j < 4; ++j) {
      int gn = n0 + wn + j * 16 + l16;     // d index
#pragma unroll
      for (int r = 0; r < 4; ++r) {
        Q[(size_t)(t0 + r) * Dn + gn] = f2b(acc[0][i][j][r]);
        K[(size_t)(t0 + r) * Dn + gn] = f2b(acc[1][i][j][r]);
      }
      *(ushort4*)&Vt[((size_t)b * Dn + gn) * Sn + s0] =
          make_ushort4(f2b(acc[2][i][j][0]), f2b(acc[2][i][j][1]),
                       f2b(acc[2][i][j][2]), f2b(acc[2][i][j][3]));
    }
  }
}

// ---- scores = Q_b @ K_b^T / sqrt(D); z = batch. Masked tiles: no compute, NO write
// (softmax masks by index and never reads them).
__global__ __launch_bounds__(256, 2)
void scores_kernel(const u16* __restrict__ Q, const u16* __restrict__ K,
                   float* __restrict__ Sc) {
  const int b = blockIdx.z;
  const int m0 = blockIdx.y * BM, n0 = blockIdx.x * BM;
  if (n0 > m0 + (BM - 1)) return;  // fully above diagonal
  __shared__ __align__(16) u16 As[128 * 64], Bs[128 * 64];
  floatx4 acc[1][4][4] = {};
  gemm_multi<1, 64>(Q + (size_t)b * Sn * Dn + (size_t)m0 * Dn,
                    K + (size_t)b * Sn * Dn + (size_t)n0 * Dn, nullptr, nullptr,
                    Dn, Dn, Dn, As, Bs, acc);

  float* C = Sc + (size_t)b * Sn * Sn;
  const float inv_scale = 0.022097086912079608f;  // 1/sqrt(2048)
  const int lane = threadIdx.x & 63, wave = threadIdx.x >> 6;
  const int wm = (wave >> 1) * 64, wn = (wave & 1) * 64;
  const int quad = lane >> 4, l16 = lane & 15;
#pragma unroll
  for (int i = 0; i < 4; ++i) {
    int gm0 = m0 + wm + i * 16 + quad * 4;
#pragma unroll
    for (int j = 0; j < 4; ++j) {
      int gn = n0 + wn + j * 16 + l16;
#pragma unroll
      for (int r = 0; r < 4; ++r)
        C[(size_t)(gm0 + r) * Sn + gn] = acc[0][i][j][r] * inv_scale;
    }
  }
}

// ---- row softmax, causal by index. Row r: reads cols [0, r], writes bf16 attn
// over [0, P) where P = round_up(r+1, 128) (exactly what pv reads); zeros past r.
__global__ __launch_bounds__(256)
void softmax_kernel(float* __restrict__ Sc) {
  const int gr = blockIdx.x;            // b*Sn + s
  const int r = gr & (Sn - 1);          // row within batch
  float* sr = Sc + (size_t)gr * Sn;
  const int t = threadIdx.x;
  const int base0 = 4 * t, base1 = 1024 + 4 * t;
  const int P = ((r >> 7) + 1) << 7;    // pv read length for this row

  float4 v0 = make_float4(-1e30f, -1e30f, -1e30f, -1e30f);
  float4 v1 = v0;
  if (base0 <= r) {
    v0 = ((const float4*)sr)[t];
    if (base0 + 1 > r) v0.y = -1e30f;
    if (base0 + 2 > r) v0.z = -1e30f;
    if (base0 + 3 > r) v0.w = -1e30f;
  }
  if (base1 <= r) {
    v1 = ((const float4*)sr)[t + 256];
    if (base1 + 1 > r) v1.y = -1e30f;
    if (base1 + 2 > r) v1.z = -1e30f;
    if (base1 + 3 > r) v1.w = -1e30f;
  }
  float m = fmaxf(fmaxf(fmaxf(v0.x, v0.y), fmaxf(v0.z, v0.w)),
                  fmaxf(fmaxf(v1.x, v1.y), fmaxf(v1.z, v1.w)));
#pragma unroll
  for (int off = 32; off; off >>= 1) m = fmaxf(m, __shfl_xor(m, off));
  __shared__ float redm[4], reds[4];
  if ((t & 63) == 0) redm[t >> 6] = m;
  __syncthreads();
  m = fmaxf(fmaxf(redm[0], redm[1]), fmaxf(redm[2], redm[3]));

  float e[8];
  e[0] = __expf(v0.x - m); e[1] = __expf(v0.y - m);
  e[2] = __expf(v0.z - m); e[3] = __expf(v0.w - m);
  e[4] = __expf(v1.x - m); e[5] = __expf(v1.y - m);
  e[6] = __expf(v1.z - m); e[7] = __expf(v1.w - m);
  float s = ((e[0] + e[1]) + (e[2] + e[3])) + ((e[4] + e[5]) + (e[6] + e[7]));
#pragma unroll
  for (int off = 32; off; off >>= 1) s += __shfl_xor(s, off);
  if ((t & 63) == 0) reds[t >> 6] = s;
  __syncthreads();
  s = (reds[0] + reds[1]) + (reds[2] + reds[3]);
  float inv = 1.0f / s;

  u16* ar = (u16*)sr;  // in-place bf16; all reads above
  if (base0 < P)
    *(ushort4*)&ar[base0] =
        make_ushort4(f2b(e[0] * inv), f2b(e[1] * inv), f2b(e[2] * inv), f2b(e[3] * inv));
  if (base1 < P)
    *(ushort4*)&ar[base1] =
        make_ushort4(f2b(e[4] * inv), f2b(e[5] * inv), f2b(e[6] * inv), f2b(e[7] * inv));
}

// ---- out_b = attn @ V via Vt; 2-wide in N (256 cols/block); K truncated at diagonal.
__global__ __launch_bounds__(256, 2)
void pv_kernel(const float* __restrict__ Sc, const u16* __restrict__ Vt,
               float* __restrict__ out) {
  const int b = blockIdx.z;
  const int m0 = blockIdx.y * BM, n0 = blockIdx.x * 256;
  __shared__ __align__(16) u16 As[128 * 64], Bs[2 * 128 * 64];  // 16 + 32 KB
  floatx4 acc[2][4][4] = {};
  const u16* P = (const u16*)(Sc + (size_t)b * Sn * Sn);  // bf16 attn, pitch 2*Sn
  const u16* Vb = Vt + (size_t)b * Dn * Sn;
  gemm_multi<2, 64>(P + (size_t)m0 * 2 * Sn, Vb + (size_t)n0 * Sn,
                    Vb + (size_t)(n0 + 128) * Sn, nullptr,
                    2 * Sn, Sn, m0 + BM, As, Bs, acc);

  const int lane = threadIdx.x & 63, wave = threadIdx.x >> 6;
  const int wm = (wave >> 1) * 64, wn = (wave & 1) * 64;
  const int quad = lane >> 4, l16 = lane & 15;
  float* ob = out + (size_t)b * Sn * Dn;
#pragma unroll
  for (int z = 0; z < 2; ++z)
#pragma unroll
    for (int i = 0; i < 4; ++i) {
      int gm0 = m0 + wm + i * 16 + quad * 4;
#pragma unroll
      for (int j = 0; j < 4; ++j) {
        int gn = n0 + z * 128 + wn + j * 16 + l16;
#pragma unroll
        for (int r = 0; r < 4; ++r)
          ob[(size_t)(gm0 + r) * Dn + gn] = acc[z][i][j][r];
      }
    }
}

extern "C" void kernel_launch(void* const* d_in, const int* in_sizes, int n_in,
                              void* d_out, int out_size, void* d_ws, size_t ws_size,
                              hipStream_t stream) {
  const float* x  = (const float*)d_in[0];   // setup_inputs order: x, Wk, Wq, Wv (fp32)
  const float* Wk = (const float*)d_in[1];
  const float* Wq = (const float*)d_in[2];
  const float* Wv = (const float*)d_in[3];
  float* out = (float*)d_out;

  const int nW = Dn * En;                    // 4M elems per weight
  u16* Wqb = (u16*)d_ws;
  u16* Wkb = Wqb + (size_t)nW;
  u16* Wvb = Wkb + (size_t)nW;
  u16* xb  = Wvb + (size_t)nW;                       // [8192][2048]
  u16* Kall = xb + (size_t)Bn * Sn * En;             // [8192][2048]
  u16* Vtall = Kall + (size_t)Bn * Sn * Dn;          // [b][d][s]
  float* Sc = (float*)(Vtall + (size_t)Bn * Dn * Sn);  // [b][s][s]
  u16* Qall = (u16*)out;                             // pv overwrites after scores

  dim3 blk(256);
  cvt_kernel<<<nW / 2048, blk, 0, stream>>>(Wq, Wqb, nW);
  cvt_kernel<<<nW / 2048, blk, 0, stream>>>(Wk, Wkb, nW);
  cvt_kernel<<<nW / 2048, blk, 0, stream>>>(Wv, Wvb, nW);
  cvt_kernel<<<(Bn * Sn * En) / 2048, blk, 0, stream>>>(x, xb, Bn * Sn * En);
  proj3_kernel<<<dim3(Dn / BM, (Bn * Sn) / BM), blk, 0, stream>>>(
      xb, Wqb, Wkb, Wvb, Qall, Kall, Vtall);
  scores_kernel<<<dim3(Sn / BM, Sn / BM, Bn), blk, 0, stream>>>(Qall, Kall, Sc);
  softmax_kernel<<<dim3(Bn * Sn), blk, 0, stream>>>(Sc);
  pv_kernel<<<dim3(Dn / 256, Sn / BM, Bn), blk, 0, stream>>>(Sc, Vtall, out);
}